// Round 5
// baseline (412.590 us; speedup 1.0000x reference)
//
#include <hip/hip_runtime.h>
#include <cstdint>
#include <math.h>

constexpr float NEG_SLOPE = 0.2f;

__device__ __forceinline__ float lrelu(float v) { return v > 0.0f ? v : NEG_SLOPE * v; }

// ---------------- K1: per-node init + mask bits (one wave per node) ----------------
__global__ void k_init(const float* __restrict__ mask,
                       unsigned long long* __restrict__ mbits,
                       unsigned long long* __restrict__ magg,
                       int* __restrict__ deg, int* __restrict__ startg, int N)
{
    if (blockIdx.x == 0 && threadIdx.x < 64) startg[threadIdx.x] = N;
    int wid  = (blockIdx.x * blockDim.x + threadIdx.x) >> 6;
    int lane = threadIdx.x & 63;
    if (wid >= N) return;
    float v = mask[(size_t)wid * 64 + lane];
    unsigned long long b = __ballot(v > 0.0f);
    if (lane == 0) { mbits[wid] = b; magg[wid] = 0ULL; deg[wid] = 0; }
}

// ---------------- K2: edge pass: mask OR scatter (col->row) + in-degree histogram (by col) ----
__global__ void k_edge_prep(const int* __restrict__ ei,
                            const unsigned long long* __restrict__ mbits,
                            unsigned long long* __restrict__ magg,
                            int* __restrict__ deg, int E)
{
    int e = blockIdx.x * blockDim.x + threadIdx.x;
    if (e >= E) return;
    int r = ei[e];
    int c = ei[E + e];
    atomicOr(magg + r, mbits[c]);
    atomicAdd(deg + c, 1);
}

// ---------------- K3 (fused): xw = x @ W_gat^T  with W in REGISTERS, + a_s/a_d + boundary ----
__launch_bounds__(256, 4)
__global__ void k_gemm1f(const float* __restrict__ x, const float* __restrict__ Wg,
                         const float* __restrict__ att_src, const float* __restrict__ att_dst,
                         const int* __restrict__ batch_idx,
                         float* __restrict__ xw, float* __restrict__ a_s, float* __restrict__ a_d,
                         int* __restrict__ startg, int N)
{
    __shared__ float xs[64 * 64];
    const int tid = threadIdx.x;
    const int r0  = blockIdx.x * 64;
    const int lane = tid & 63;
    const int h    = tid >> 6;     // wave index == head index

    float w[64];
    #pragma unroll
    for (int q = 0; q < 16; ++q) {
        float4 wv = *(const float4*)&Wg[(size_t)tid * 64 + 4 * q];
        w[4*q+0] = wv.x; w[4*q+1] = wv.y; w[4*q+2] = wv.z; w[4*q+3] = wv.w;
    }
    const float as_c = att_src[tid];
    const float ad_c = att_dst[tid];

    for (int idx = tid; idx < 64 * 64; idx += 256) {
        int r = idx >> 6;
        xs[idx] = (r0 + r < N) ? x[(size_t)(r0 + r) * 64 + (idx & 63)] : 0.0f;
    }
    if (tid < 64 && (r0 + tid) < N) {
        int i = r0 + tid;
        int b = batch_idx[i];
        int pb = (i > 0) ? batch_idx[i - 1] : -1;
        if (b != pb) startg[b] = i;
    }
    __syncthreads();

    for (int r = 0; r < 64; r += 2) {
        float acc0 = 0.0f, acc1 = 0.0f;
        #pragma unroll
        for (int q = 0; q < 16; ++q) {
            float4 xa = *(const float4*)&xs[r * 64 + 4 * q];
            float4 xb = *(const float4*)&xs[(r + 1) * 64 + 4 * q];
            acc0 += xa.x * w[4*q] + xa.y * w[4*q+1] + xa.z * w[4*q+2] + xa.w * w[4*q+3];
            acc1 += xb.x * w[4*q] + xb.y * w[4*q+1] + xb.z * w[4*q+2] + xb.w * w[4*q+3];
        }
        float ps0 = acc0 * as_c, pd0 = acc0 * ad_c;
        float ps1 = acc1 * as_c, pd1 = acc1 * ad_c;
        #pragma unroll
        for (int o = 1; o < 64; o <<= 1) {
            ps0 += __shfl_xor(ps0, o); pd0 += __shfl_xor(pd0, o);
            ps1 += __shfl_xor(ps1, o); pd1 += __shfl_xor(pd1, o);
        }
        int ra = r0 + r;
        if (ra < N) {
            xw[(size_t)ra * 256 + tid] = acc0;
            if (lane == 0) { a_s[(size_t)ra * 4 + h] = ps0; a_d[(size_t)ra * 4 + h] = pd0; }
        }
        if (ra + 1 < N) {
            xw[(size_t)(ra + 1) * 256 + tid] = acc1;
            if (lane == 0) { a_s[(size_t)(ra + 1) * 4 + h] = ps1; a_d[(size_t)(ra + 1) * 4 + h] = pd1; }
        }
    }
}

// ---------------- K5/K6/K7: exclusive scan of deg -> off, cursor; graph inv_sqrt --------
__global__ void k_scan1(const int* __restrict__ deg, int* __restrict__ off,
                        int* __restrict__ bsum, int N)
{
    __shared__ int s[256];
    int t = threadIdx.x;
    int i = blockIdx.x * 256 + t;
    int v = (i < N) ? deg[i] : 0;
    s[t] = v; __syncthreads();
    for (int o = 1; o < 256; o <<= 1) {
        int u = (t >= o) ? s[t - o] : 0;
        __syncthreads();
        s[t] += u;
        __syncthreads();
    }
    int incl = s[t];
    if (i < N) off[i] = incl - v;
    if (t == 255) bsum[blockIdx.x] = incl;
}

__global__ void k_scan2(const int* __restrict__ bsum, int* __restrict__ bpre,
                        int* __restrict__ off, const int* __restrict__ startg,
                        float* __restrict__ invs, int NB, int N)
{
    __shared__ int s[256];
    int t = threadIdx.x;
    int v = (t < NB) ? bsum[t] : 0;
    s[t] = v; __syncthreads();
    for (int o = 1; o < 256; o <<= 1) {
        int u = (t >= o) ? s[t - o] : 0;
        __syncthreads();
        s[t] += u;
        __syncthreads();
    }
    if (t < NB) bpre[t] = s[t] - v;
    if (t == 255) off[N] = s[255];
    if (t < 64) {
        int st = startg[t];
        int en = N;
        for (int g2 = t + 1; g2 < 64; ++g2) en = min(en, startg[g2]);
        int d = en - st;
        float dv = (d > 0) ? (float)d : 1.0f;
        invs[t] = 1.0f / sqrtf(dv);
    }
}

__global__ void k_scan3(int* __restrict__ off, int* __restrict__ cursor,
                        const int* __restrict__ bpre, int N)
{
    int i = blockIdx.x * blockDim.x + threadIdx.x;
    if (i >= N) return;
    int v = off[i] + bpre[blockIdx.x];
    off[i] = v;
    cursor[i] = v;
}

// ---------------- K8: CSR fill (dst-sorted source list) ----------------
__global__ void k_fill(const int* __restrict__ ei, int* __restrict__ cursor,
                       int* __restrict__ csr, int E)
{
    int e = blockIdx.x * blockDim.x + threadIdx.x;
    if (e >= E) return;
    int r = ei[e];
    int c = ei[E + e];
    int pos = atomicAdd(cursor + c, 1);
    csr[pos] = r;
}

// ---------------- K9 (v3): round-3 inner loop, head-split across XCD phases ----------
// Blocks with (blockIdx&7) < 4 process heads {0,1} (features 0..127); the rest
// heads {2,3}. Per-head arithmetic (chunking, edge order, reduction order) is
// IDENTICAL to the round-3 passing kernel — only the wave assignment changes.
// Each XCD touches only half of xw -> per-XCD compulsory fetch halves; per-edge
// cost drops to 2 gathers + 3 shfls (from 4 + 5).
__launch_bounds__(256)
__global__ void k_main3(const float* __restrict__ xw,
                        const float* __restrict__ a_s,
                        const float* __restrict__ a_d,
                        const int* __restrict__ off,
                        const int* __restrict__ csr,
                        const unsigned long long* __restrict__ magg,
                        const float* __restrict__ bias,
                        float* __restrict__ tb, int N)
{
    const int bid   = blockIdx.x;
    const int xcd   = bid & 7;
    const int phase = (xcd >= 4) ? 1 : 0;            // head pair {2p, 2p+1}
    const int pblk  = (bid >> 3) * 4 + (xcd & 3);    // block index within phase
    const int lane  = threadIdx.x & 63;
    const int wv    = threadIdx.x >> 6;
    const int wid   = pblk * 4 + wv;
    const int nw    = 8192;                          // waves per phase

    const int fbase = phase * 128;                   // feature offset of this head pair
    const float b0c = bias[fbase + lane];
    const float b1c = bias[fbase + 64 + lane];

    for (int i = wid; i < N; i += nw) {
        const int beg = off[i], end = off[i + 1];
        const float2 ad2 = *(const float2*)(a_d + (size_t)i * 4 + phase * 2);
        const float2 as2 = *(const float2*)(a_s + (size_t)i * 4 + phase * 2);
        const float exa = __expf(lrelu(as2.x + ad2.x));
        const float exb = __expf(lrelu(as2.y + ad2.y));

        const float* xwi = xw + (size_t)i * 256 + fbase;
        float acc0 = exa * xwi[lane];
        float acc1 = exb * xwi[64 + lane];
        float s0 = 0.f, s1 = 0.f;

        for (int kc = beg; kc < end; kc += 64) {
            const int cnt = min(64, end - kc);
            int sreg = 0; float e0 = 0.f, e1 = 0.f;
            if (lane < cnt) {
                sreg = csr[kc + lane];
                const float2 g = *(const float2*)(a_s + (size_t)sreg * 4 + phase * 2);
                e0 = __expf(lrelu(g.x + ad2.x));
                e1 = __expf(lrelu(g.y + ad2.y));
            }
            s0 += e0; s1 += e1;
            for (int j = 0; j < cnt; ++j) {
                int   s  = __shfl(sreg, j);
                float w0 = __shfl(e0, j);
                float w1 = __shfl(e1, j);
                const float* xws = xw + (size_t)s * 256 + fbase + lane;
                acc0 += w0 * xws[0];
                acc1 += w1 * xws[64];
            }
        }
        #pragma unroll
        for (int o = 1; o < 64; o <<= 1) { s0 += __shfl_xor(s0, o); s1 += __shfl_xor(s1, o); }
        s0 += exa; s1 += exb;   // self-loop terms, counted once
        const float r0 = 1.0f / (s0 + 1e-16f);
        const float r1 = 1.0f / (s1 + 1e-16f);

        const unsigned long long mb = magg[i];
        const float mbit = (float)((mb >> lane) & 1ULL);   // mask feature = col & 63 = lane
        const size_t ob = (size_t)i * 256 + fbase + lane;
        tb[ob     ] = (acc0 * r0 + b0c) * mbit;
        tb[ob + 64] = (acc1 * r1 + b1c) * mbit;
    }
}

// ---------------- K10: out = tb @ W_lin^T + b_lin, * inv_sqrt[batch] (reg-weight) -------
__launch_bounds__(256, 4)
__global__ void k_gemm2r(const float* __restrict__ tb, const float* __restrict__ Wl,
                         const float* __restrict__ bl,
                         const int* __restrict__ batch_idx, const float* __restrict__ invs,
                         float* __restrict__ out, int N)
{
    __shared__ float ts[32 * 256];
    const int tid  = threadIdx.x;
    const int wv   = tid >> 6;
    const int lane = tid & 63;
    const int cl   = lane & 15;
    const int q    = lane >> 4;
    const int c    = wv * 16 + cl;
    const int r0   = blockIdx.x * 32;

    float4 w4[16];
    #pragma unroll
    for (int m = 0; m < 8; ++m) {
        w4[m*2+0] = *(const float4*)&Wl[(size_t)c * 256 + m*32 + q*8 + 0];
        w4[m*2+1] = *(const float4*)&Wl[(size_t)c * 256 + m*32 + q*8 + 4];
    }
    const float blc = bl[c];

    const float4* tb4 = (const float4*)tb;
    float4* ts4 = (float4*)ts;
    #pragma unroll
    for (int it = 0; it < 8; ++it) {
        int idx = tid + it * 256;
        int row = idx >> 6;
        float4 v = make_float4(0.f, 0.f, 0.f, 0.f);
        if (r0 + row < N) v = tb4[(size_t)r0 * 64 + idx];
        ts4[idx] = v;
    }
    __syncthreads();

    #pragma unroll
    for (int rb = 0; rb < 32; rb += 4) {
        float p[4];
        #pragma unroll
        for (int rr = 0; rr < 4; ++rr) {
            const float4* tr = ts4 + (rb + rr) * 64 + q * 2;
            float a = 0.f;
            #pragma unroll
            for (int m = 0; m < 8; ++m) {
                float4 t0 = tr[m*8 + 0];
                float4 t1 = tr[m*8 + 1];
                float4 u0 = w4[m*2+0], u1 = w4[m*2+1];
                a += t0.x*u0.x + t0.y*u0.y + t0.z*u0.z + t0.w*u0.w
                   + t1.x*u1.x + t1.y*u1.y + t1.z*u1.z + t1.w*u1.w;
            }
            a += __shfl_xor(a, 16);
            a += __shfl_xor(a, 32);
            p[rr] = a;
        }
        int rr  = lane >> 4;
        float val = (rr == 0) ? p[0] : (rr == 1) ? p[1] : (rr == 2) ? p[2] : p[3];
        int row = r0 + rb + rr;
        if (row < N) {
            float sc = invs[batch_idx[row]];
            out[(size_t)row * 64 + c] = (val + blc) * sc;
        }
    }
}

// ---------------- launcher ----------------
extern "C" void kernel_launch(void* const* d_in, const int* in_sizes, int n_in,
                              void* d_out, int out_size, void* d_ws, size_t ws_size,
                              hipStream_t stream)
{
    const float* x      = (const float*)d_in[0];
    const float* mask   = (const float*)d_in[1];
    const int*   ei     = (const int*)d_in[2];
    const int*   batch  = (const int*)d_in[3];
    const float* Wg     = (const float*)d_in[4];
    const float* att_s  = (const float*)d_in[5];
    const float* att_d  = (const float*)d_in[6];
    const float* bias_g = (const float*)d_in[7];
    const float* Wl     = (const float*)d_in[8];
    const float* bl     = (const float*)d_in[9];
    float* out = (float*)d_out;

    const int N = in_sizes[0] / 64;   // 50000
    const int E = in_sizes[2] / 2;    // 800000

    char* w = (char*)d_ws;
    auto alloc = [&](size_t bytes) { char* p = w; w += (bytes + 255) & ~(size_t)255; return p; };
    float* xw    = (float*)alloc((size_t)N * 256 * 4);
    float* tbuf  = (float*)alloc((size_t)N * 256 * 4);
    float* a_s   = (float*)alloc((size_t)N * 4 * 4);
    float* a_d   = (float*)alloc((size_t)N * 4 * 4);
    unsigned long long* mbits = (unsigned long long*)alloc((size_t)N * 8);
    unsigned long long* magg  = (unsigned long long*)alloc((size_t)N * 8);
    int* deg    = (int*)alloc((size_t)N * 4);
    int* off    = (int*)alloc((size_t)(N + 1) * 4);
    int* cursor = (int*)alloc((size_t)N * 4);
    int* csr    = (int*)alloc((size_t)E * 4);
    int* bsum   = (int*)alloc(256 * 4);
    int* bpre   = (int*)alloc(256 * 4);
    int* startg = (int*)alloc(64 * 4);
    float* invs = (float*)alloc(64 * 4);

    int nbN4  = (N + 3) / 4;       // one wave per node, 4 waves/block
    int nb256 = (N + 255) / 256;

    k_init<<<nbN4, 256, 0, stream>>>(mask, mbits, magg, deg, startg, N);
    k_edge_prep<<<(E + 255) / 256, 256, 0, stream>>>(ei, mbits, magg, deg, E);
    k_gemm1f<<<(N + 63) / 64, 256, 0, stream>>>(x, Wg, att_s, att_d, batch, xw, a_s, a_d, startg, N);
    k_scan1<<<nb256, 256, 0, stream>>>(deg, off, bsum, N);
    k_scan2<<<1, 256, 0, stream>>>(bsum, bpre, off, startg, invs, nb256, N);
    k_scan3<<<nb256, 256, 0, stream>>>(off, cursor, bpre, N);
    k_fill<<<(E + 255) / 256, 256, 0, stream>>>(ei, cursor, csr, E);
    k_main3<<<4096, 256, 0, stream>>>(xw, a_s, a_d, off, csr, magg, bias_g, tbuf, N);
    k_gemm2r<<<(N + 31) / 32, 256, 0, stream>>>(tbuf, Wl, bl, batch, invs, out, N);
}

// Round 6
// 329.428 us; speedup vs baseline: 1.2524x; 1.2524x over previous
//
#include <hip/hip_runtime.h>
#include <cstdint>
#include <math.h>

constexpr float NEG_SLOPE = 0.2f;

__device__ __forceinline__ float lrelu(float v) { return v > 0.0f ? v : NEG_SLOPE * v; }

// bf16 pack/unpack (RNE)
__device__ __forceinline__ unsigned short f2bf(float f) {
    uint32_t u = __float_as_uint(f);
    uint32_t r = (u + 0x7fffu + ((u >> 16) & 1u)) >> 16;
    return (unsigned short)r;
}
__device__ __forceinline__ float bflo(uint32_t v) { return __uint_as_float(v << 16); }
__device__ __forceinline__ float bfhi(uint32_t v) { return __uint_as_float(v & 0xffff0000u); }

// ---------------- K1: per-node init + mask bits (one wave per node) ----------------
__global__ void k_init(const float* __restrict__ mask,
                       unsigned long long* __restrict__ mbits,
                       unsigned long long* __restrict__ magg,
                       int* __restrict__ deg, int* __restrict__ startg, int N)
{
    if (blockIdx.x == 0 && threadIdx.x < 64) startg[threadIdx.x] = N;
    int wid  = (blockIdx.x * blockDim.x + threadIdx.x) >> 6;
    int lane = threadIdx.x & 63;
    if (wid >= N) return;
    float v = mask[(size_t)wid * 64 + lane];
    unsigned long long b = __ballot(v > 0.0f);
    if (lane == 0) { mbits[wid] = b; magg[wid] = 0ULL; deg[wid] = 0; }
}

// ---------------- K2: edge pass: mask OR scatter (col->row) + in-degree histogram ----
// check-then-set: skip the atomicOr when bits are already present (idempotent OR;
// stale reads only cause a redundant atomic, never a missing bit).
__global__ void k_edge_prep(const int* __restrict__ ei,
                            const unsigned long long* __restrict__ mbits,
                            unsigned long long* __restrict__ magg,
                            int* __restrict__ deg, int E)
{
    int e = blockIdx.x * blockDim.x + threadIdx.x;
    if (e >= E) return;
    int r = ei[e];
    int c = ei[E + e];
    unsigned long long b = mbits[c];
    if ((magg[r] & b) != b) atomicOr(magg + r, b);
    atomicAdd(deg + c, 1);
}

// ---------------- K3 (fused): xw(bf16-packed) = x @ W_gat^T, + a_s/a_d + boundary ----
// xwp layout: row i = 128 uints; uint (hp*64+d) packs heads {2hp (low), 2hp+1 (high)}
// of feature d.
__launch_bounds__(256, 4)
__global__ void k_gemm1f(const float* __restrict__ x, const float* __restrict__ Wg,
                         const float* __restrict__ att_src, const float* __restrict__ att_dst,
                         const int* __restrict__ batch_idx,
                         uint32_t* __restrict__ xwp, float* __restrict__ a_s, float* __restrict__ a_d,
                         int* __restrict__ startg, int N)
{
    __shared__ float xs[64 * 64];
    const int tid = threadIdx.x;
    const int r0  = blockIdx.x * 64;
    const int lane = tid & 63;
    const int h    = tid >> 6;     // wave index == head index
    const int hp   = h >> 1;
    const int sel  = h & 1;

    float w[64];
    #pragma unroll
    for (int q = 0; q < 16; ++q) {
        float4 wv = *(const float4*)&Wg[(size_t)tid * 64 + 4 * q];
        w[4*q+0] = wv.x; w[4*q+1] = wv.y; w[4*q+2] = wv.z; w[4*q+3] = wv.w;
    }
    const float as_c = att_src[tid];
    const float ad_c = att_dst[tid];

    for (int idx = tid; idx < 64 * 64; idx += 256) {
        int r = idx >> 6;
        xs[idx] = (r0 + r < N) ? x[(size_t)(r0 + r) * 64 + (idx & 63)] : 0.0f;
    }
    if (tid < 64 && (r0 + tid) < N) {
        int i = r0 + tid;
        int b = batch_idx[i];
        int pb = (i > 0) ? batch_idx[i - 1] : -1;
        if (b != pb) startg[b] = i;
    }
    __syncthreads();

    unsigned short* xws = (unsigned short*)xwp;
    const int us_idx = (hp * 64 + lane) * 2 + sel;   // ushort index within row (stride 256)

    for (int r = 0; r < 64; r += 2) {
        float acc0 = 0.0f, acc1 = 0.0f;
        #pragma unroll
        for (int q = 0; q < 16; ++q) {
            float4 xa = *(const float4*)&xs[r * 64 + 4 * q];
            float4 xb = *(const float4*)&xs[(r + 1) * 64 + 4 * q];
            acc0 += xa.x * w[4*q] + xa.y * w[4*q+1] + xa.z * w[4*q+2] + xa.w * w[4*q+3];
            acc1 += xb.x * w[4*q] + xb.y * w[4*q+1] + xb.z * w[4*q+2] + xb.w * w[4*q+3];
        }
        float ps0 = acc0 * as_c, pd0 = acc0 * ad_c;
        float ps1 = acc1 * as_c, pd1 = acc1 * ad_c;
        #pragma unroll
        for (int o = 1; o < 64; o <<= 1) {
            ps0 += __shfl_xor(ps0, o); pd0 += __shfl_xor(pd0, o);
            ps1 += __shfl_xor(ps1, o); pd1 += __shfl_xor(pd1, o);
        }
        int ra = r0 + r;
        if (ra < N) {
            xws[(size_t)ra * 256 + us_idx] = f2bf(acc0);
            if (lane == 0) { a_s[(size_t)ra * 4 + h] = ps0; a_d[(size_t)ra * 4 + h] = pd0; }
        }
        if (ra + 1 < N) {
            xws[(size_t)(ra + 1) * 256 + us_idx] = f2bf(acc1);
            if (lane == 0) { a_s[(size_t)(ra + 1) * 4 + h] = ps1; a_d[(size_t)(ra + 1) * 4 + h] = pd1; }
        }
    }
}

// ---------------- K5/K6/K7: exclusive scan of deg -> off, cursor; graph inv_sqrt --------
__global__ void k_scan1(const int* __restrict__ deg, int* __restrict__ off,
                        int* __restrict__ bsum, int N)
{
    __shared__ int s[256];
    int t = threadIdx.x;
    int i = blockIdx.x * 256 + t;
    int v = (i < N) ? deg[i] : 0;
    s[t] = v; __syncthreads();
    for (int o = 1; o < 256; o <<= 1) {
        int u = (t >= o) ? s[t - o] : 0;
        __syncthreads();
        s[t] += u;
        __syncthreads();
    }
    int incl = s[t];
    if (i < N) off[i] = incl - v;
    if (t == 255) bsum[blockIdx.x] = incl;
}

__global__ void k_scan2(const int* __restrict__ bsum, int* __restrict__ bpre,
                        int* __restrict__ off, const int* __restrict__ startg,
                        float* __restrict__ invs, int NB, int N)
{
    __shared__ int s[256];
    int t = threadIdx.x;
    int v = (t < NB) ? bsum[t] : 0;
    s[t] = v; __syncthreads();
    for (int o = 1; o < 256; o <<= 1) {
        int u = (t >= o) ? s[t - o] : 0;
        __syncthreads();
        s[t] += u;
        __syncthreads();
    }
    if (t < NB) bpre[t] = s[t] - v;
    if (t == 255) off[N] = s[255];
    if (t < 64) {
        int st = startg[t];
        int en = N;
        for (int g2 = t + 1; g2 < 64; ++g2) en = min(en, startg[g2]);
        int d = en - st;
        float dv = (d > 0) ? (float)d : 1.0f;
        invs[t] = 1.0f / sqrtf(dv);
    }
}

__global__ void k_scan3(int* __restrict__ off, int* __restrict__ cursor,
                        const int* __restrict__ bpre, int N)
{
    int i = blockIdx.x * blockDim.x + threadIdx.x;
    if (i >= N) return;
    int v = off[i] + bpre[blockIdx.x];
    off[i] = v;
    cursor[i] = v;
}

// ---------------- K8: CSR fill (dst-sorted source list) ----------------
__global__ void k_fill(const int* __restrict__ ei, int* __restrict__ cursor,
                       int* __restrict__ csr, int E)
{
    int e = blockIdx.x * blockDim.x + threadIdx.x;
    if (e >= E) return;
    int r = ei[e];
    int c = ei[E + e];
    int pos = atomicAdd(cursor + c, 1);
    csr[pos] = r;
}

// ---------------- K9 (v4): bf16-packed gathers, 4-edge unroll, head-pair phases -------
__launch_bounds__(256)
__global__ void k_main4(const uint32_t* __restrict__ xwp,
                        const float* __restrict__ a_s,
                        const float* __restrict__ a_d,
                        const int* __restrict__ off,
                        const int* __restrict__ csr,
                        const unsigned long long* __restrict__ magg,
                        const float* __restrict__ bias,
                        float* __restrict__ tb, int N)
{
    const int bid   = blockIdx.x;
    const int xcd   = bid & 7;
    const int phase = (xcd >= 4) ? 1 : 0;            // head pair {2p, 2p+1}
    const int pblk  = (bid >> 3) * 4 + (xcd & 3);
    const int lane  = threadIdx.x & 63;
    const int wv    = threadIdx.x >> 6;
    const int wid   = pblk * 4 + wv;
    const int nw    = 8192;                          // waves per phase

    const int fbase = phase * 128;
    const float b0c = bias[fbase + lane];
    const float b1c = bias[fbase + 64 + lane];
    const uint32_t* base = xwp + (size_t)phase * 64 + lane;   // row stride 128 uints

    for (int i = wid; i < N; i += nw) {
        const int beg = off[i], end = off[i + 1];
        const float2 ad2 = *(const float2*)(a_d + (size_t)i * 4 + phase * 2);
        const float2 as2 = *(const float2*)(a_s + (size_t)i * 4 + phase * 2);
        const float exa = __expf(lrelu(as2.x + ad2.x));
        const float exb = __expf(lrelu(as2.y + ad2.y));

        uint32_t sv = base[(size_t)i * 128];
        float accA0 = exa * bflo(sv), accA1 = exb * bfhi(sv);
        float accB0 = 0.f, accB1 = 0.f, accC0 = 0.f, accC1 = 0.f, accD0 = 0.f, accD1 = 0.f;
        float s0 = 0.f, s1 = 0.f;

        for (int kc = beg; kc < end; kc += 64) {
            const int cnt = min(64, end - kc);
            int sreg = 0; float e0 = 0.f, e1 = 0.f;
            if (lane < cnt) {
                sreg = csr[kc + lane];
                const float2 g = *(const float2*)(a_s + (size_t)sreg * 4 + phase * 2);
                e0 = __expf(lrelu(g.x + ad2.x));
                e1 = __expf(lrelu(g.y + ad2.y));
            }
            s0 += e0; s1 += e1;

            int j = 0;
            for (; j + 4 <= cnt; j += 4) {
                int sA = __shfl(sreg, j    ), sB = __shfl(sreg, j + 1);
                int sC = __shfl(sreg, j + 2), sD = __shfl(sreg, j + 3);
                float wA0 = __shfl(e0, j    ), wA1 = __shfl(e1, j    );
                float wB0 = __shfl(e0, j + 1), wB1 = __shfl(e1, j + 1);
                float wC0 = __shfl(e0, j + 2), wC1 = __shfl(e1, j + 2);
                float wD0 = __shfl(e0, j + 3), wD1 = __shfl(e1, j + 3);
                uint32_t vA = base[(size_t)sA * 128];
                uint32_t vB = base[(size_t)sB * 128];
                uint32_t vC = base[(size_t)sC * 128];
                uint32_t vD = base[(size_t)sD * 128];
                accA0 += wA0 * bflo(vA); accA1 += wA1 * bfhi(vA);
                accB0 += wB0 * bflo(vB); accB1 += wB1 * bfhi(vB);
                accC0 += wC0 * bflo(vC); accC1 += wC1 * bfhi(vC);
                accD0 += wD0 * bflo(vD); accD1 += wD1 * bfhi(vD);
            }
            for (; j < cnt; ++j) {
                int   s  = __shfl(sreg, j);
                float w0 = __shfl(e0, j);
                float w1 = __shfl(e1, j);
                uint32_t v = base[(size_t)s * 128];
                accA0 += w0 * bflo(v);
                accA1 += w1 * bfhi(v);
            }
        }
        float acc0 = (accA0 + accB0) + (accC0 + accD0);
        float acc1 = (accA1 + accB1) + (accC1 + accD1);
        #pragma unroll
        for (int o = 1; o < 64; o <<= 1) { s0 += __shfl_xor(s0, o); s1 += __shfl_xor(s1, o); }
        s0 += exa; s1 += exb;   // self-loop terms, counted once
        const float r0 = 1.0f / (s0 + 1e-16f);
        const float r1 = 1.0f / (s1 + 1e-16f);

        const unsigned long long mb = magg[i];
        const float mbit = (float)((mb >> lane) & 1ULL);   // mask feature = col & 63 = lane
        const size_t ob = (size_t)i * 256 + fbase + lane;
        tb[ob     ] = (acc0 * r0 + b0c) * mbit;
        tb[ob + 64] = (acc1 * r1 + b1c) * mbit;
    }
}

// ---------------- K10: out = tb @ W_lin^T + b_lin, * inv_sqrt[batch] (reg-weight) -------
__launch_bounds__(256, 4)
__global__ void k_gemm2r(const float* __restrict__ tb, const float* __restrict__ Wl,
                         const float* __restrict__ bl,
                         const int* __restrict__ batch_idx, const float* __restrict__ invs,
                         float* __restrict__ out, int N)
{
    __shared__ float ts[32 * 256];
    const int tid  = threadIdx.x;
    const int wv   = tid >> 6;
    const int lane = tid & 63;
    const int cl   = lane & 15;
    const int q    = lane >> 4;
    const int c    = wv * 16 + cl;
    const int r0   = blockIdx.x * 32;

    float4 w4[16];
    #pragma unroll
    for (int m = 0; m < 8; ++m) {
        w4[m*2+0] = *(const float4*)&Wl[(size_t)c * 256 + m*32 + q*8 + 0];
        w4[m*2+1] = *(const float4*)&Wl[(size_t)c * 256 + m*32 + q*8 + 4];
    }
    const float blc = bl[c];

    const float4* tb4 = (const float4*)tb;
    float4* ts4 = (float4*)ts;
    #pragma unroll
    for (int it = 0; it < 8; ++it) {
        int idx = tid + it * 256;
        int row = idx >> 6;
        float4 v = make_float4(0.f, 0.f, 0.f, 0.f);
        if (r0 + row < N) v = tb4[(size_t)r0 * 64 + idx];
        ts4[idx] = v;
    }
    __syncthreads();

    #pragma unroll
    for (int rb = 0; rb < 32; rb += 4) {
        float p[4];
        #pragma unroll
        for (int rr = 0; rr < 4; ++rr) {
            const float4* tr = ts4 + (rb + rr) * 64 + q * 2;
            float a = 0.f;
            #pragma unroll
            for (int m = 0; m < 8; ++m) {
                float4 t0 = tr[m*8 + 0];
                float4 t1 = tr[m*8 + 1];
                float4 u0 = w4[m*2+0], u1 = w4[m*2+1];
                a += t0.x*u0.x + t0.y*u0.y + t0.z*u0.z + t0.w*u0.w
                   + t1.x*u1.x + t1.y*u1.y + t1.z*u1.z + t1.w*u1.w;
            }
            a += __shfl_xor(a, 16);
            a += __shfl_xor(a, 32);
            p[rr] = a;
        }
        int rr  = lane >> 4;
        float val = (rr == 0) ? p[0] : (rr == 1) ? p[1] : (rr == 2) ? p[2] : p[3];
        int row = r0 + rb + rr;
        if (row < N) {
            float sc = invs[batch_idx[row]];
            out[(size_t)row * 64 + c] = (val + blc) * sc;
        }
    }
}

// ---------------- launcher ----------------
extern "C" void kernel_launch(void* const* d_in, const int* in_sizes, int n_in,
                              void* d_out, int out_size, void* d_ws, size_t ws_size,
                              hipStream_t stream)
{
    const float* x      = (const float*)d_in[0];
    const float* mask   = (const float*)d_in[1];
    const int*   ei     = (const int*)d_in[2];
    const int*   batch  = (const int*)d_in[3];
    const float* Wg     = (const float*)d_in[4];
    const float* att_s  = (const float*)d_in[5];
    const float* att_d  = (const float*)d_in[6];
    const float* bias_g = (const float*)d_in[7];
    const float* Wl     = (const float*)d_in[8];
    const float* bl     = (const float*)d_in[9];
    float* out = (float*)d_out;

    const int N = in_sizes[0] / 64;   // 50000
    const int E = in_sizes[2] / 2;    // 800000

    char* w = (char*)d_ws;
    auto alloc = [&](size_t bytes) { char* p = w; w += (bytes + 255) & ~(size_t)255; return p; };
    uint32_t* xwp  = (uint32_t*)alloc((size_t)N * 128 * 4);   // packed bf16 head-pairs
    float* tbuf  = (float*)alloc((size_t)N * 256 * 4);
    float* a_s   = (float*)alloc((size_t)N * 4 * 4);
    float* a_d   = (float*)alloc((size_t)N * 4 * 4);
    unsigned long long* mbits = (unsigned long long*)alloc((size_t)N * 8);
    unsigned long long* magg  = (unsigned long long*)alloc((size_t)N * 8);
    int* deg    = (int*)alloc((size_t)N * 4);
    int* off    = (int*)alloc((size_t)(N + 1) * 4);
    int* cursor = (int*)alloc((size_t)N * 4);
    int* csr    = (int*)alloc((size_t)E * 4);
    int* bsum   = (int*)alloc(256 * 4);
    int* bpre   = (int*)alloc(256 * 4);
    int* startg = (int*)alloc(64 * 4);
    float* invs = (float*)alloc(64 * 4);

    int nbN4  = (N + 3) / 4;       // one wave per node, 4 waves/block
    int nb256 = (N + 255) / 256;

    k_init<<<nbN4, 256, 0, stream>>>(mask, mbits, magg, deg, startg, N);
    k_edge_prep<<<(E + 255) / 256, 256, 0, stream>>>(ei, mbits, magg, deg, E);
    k_gemm1f<<<(N + 63) / 64, 256, 0, stream>>>(x, Wg, att_s, att_d, batch, xwp, a_s, a_d, startg, N);
    k_scan1<<<nb256, 256, 0, stream>>>(deg, off, bsum, N);
    k_scan2<<<1, 256, 0, stream>>>(bsum, bpre, off, startg, invs, nb256, N);
    k_scan3<<<nb256, 256, 0, stream>>>(off, cursor, bpre, N);
    k_fill<<<(E + 255) / 256, 256, 0, stream>>>(ei, cursor, csr, E);
    k_main4<<<4096, 256, 0, stream>>>(xwp, a_s, a_d, off, csr, magg, bias_g, tbuf, N);
    k_gemm2r<<<(N + 31) / 32, 256, 0, stream>>>(tbuf, Wl, bl, batch, invs, out, N);
}

// Round 7
// 277.822 us; speedup vs baseline: 1.4851x; 1.1858x over previous
//
#include <hip/hip_runtime.h>
#include <cstdint>
#include <math.h>

constexpr float NEG_SLOPE = 0.2f;

__device__ __forceinline__ float lrelu(float v) { return v > 0.0f ? v : NEG_SLOPE * v; }

// bf16 pack/unpack (RNE)
__device__ __forceinline__ unsigned short f2bf(float f) {
    uint32_t u = __float_as_uint(f);
    uint32_t r = (u + 0x7fffu + ((u >> 16) & 1u)) >> 16;
    return (unsigned short)r;
}
__device__ __forceinline__ float bf2f(unsigned short v) { return __uint_as_float((uint32_t)v << 16); }
__device__ __forceinline__ float bflo(uint32_t v) { return __uint_as_float(v << 16); }
__device__ __forceinline__ float bfhi(uint32_t v) { return __uint_as_float(v & 0xffff0000u); }

typedef short bf16x8 __attribute__((ext_vector_type(8)));   // 8 bf16 (4 VGPRs) - guide §3
typedef float f32x4 __attribute__((ext_vector_type(4)));

// ---------------- K1: per-node init + mask bits (one wave per node) ----------------
__global__ void k_init(const float* __restrict__ mask,
                       unsigned long long* __restrict__ mbits,
                       unsigned long long* __restrict__ magg,
                       int* __restrict__ deg, int* __restrict__ startg, int N)
{
    if (blockIdx.x == 0 && threadIdx.x < 64) startg[threadIdx.x] = N;
    int wid  = (blockIdx.x * blockDim.x + threadIdx.x) >> 6;
    int lane = threadIdx.x & 63;
    if (wid >= N) return;
    float v = mask[(size_t)wid * 64 + lane];
    unsigned long long b = __ballot(v > 0.0f);
    if (lane == 0) { mbits[wid] = b; magg[wid] = 0ULL; deg[wid] = 0; }
}

// ---------------- K2: edge pass: mask OR scatter (col->row) + in-degree histogram ----
__global__ void k_edge_prep(const int* __restrict__ ei,
                            const unsigned long long* __restrict__ mbits,
                            unsigned long long* __restrict__ magg,
                            int* __restrict__ deg, int E)
{
    int e = blockIdx.x * blockDim.x + threadIdx.x;
    if (e >= E) return;
    int r = ei[e];
    int c = ei[E + e];
    unsigned long long b = mbits[c];
    if ((magg[r] & b) != b) atomicOr(magg + r, b);
    atomicAdd(deg + c, 1);
}

// ---------------- K_vprep: v_s/v_d = W_gat^T . att (folds att dot into x-space) -------
// a_s[i][h] = dot(xw[i,h,:], att_src[h,:]) = dot(x[i,:], v_s[h,:]) by linearity.
__global__ void k_vprep(const float* __restrict__ Wg,
                        const float* __restrict__ att_s, const float* __restrict__ att_d,
                        float* __restrict__ vs, float* __restrict__ vd)
{
    int t = threadIdx.x;           // 256 threads: (h = t>>6, k = t&63)
    int h = t >> 6, k = t & 63;
    float s = 0.f, d = 0.f;
    for (int dd = 0; dd < 64; ++dd) {
        float w = Wg[(size_t)(h * 64 + dd) * 64 + k];
        s += w * att_s[h * 64 + dd];
        d += w * att_d[h * 64 + dd];
    }
    vs[t] = s; vd[t] = d;
}

// ---------------- K_att: a_s/a_d per node, thread-per-node, no cross-lane ops ---------
__launch_bounds__(256)
__global__ void k_att(const float* __restrict__ x,
                      const float* __restrict__ vs, const float* __restrict__ vd,
                      float* __restrict__ a_s, float* __restrict__ a_d, int N)
{
    __shared__ float4 vsm[128];    // [0..63] = v_s (4 heads x 16 quads), [64..127] = v_d
    int tid = threadIdx.x;
    if (tid < 64) vsm[tid] = ((const float4*)vs)[tid];
    else if (tid < 128) vsm[tid] = ((const float4*)vd)[tid - 64];
    __syncthreads();
    int i = blockIdx.x * 256 + tid;
    if (i >= N) return;
    const float4* xr = (const float4*)(x + (size_t)i * 64);
    float s0=0,s1=0,s2=0,s3=0, d0=0,d1=0,d2=0,d3=0;
    #pragma unroll
    for (int q = 0; q < 16; ++q) {
        float4 xv = xr[q];
        float4 a0 = vsm[q], a1 = vsm[16+q], a2 = vsm[32+q], a3 = vsm[48+q];
        float4 c0 = vsm[64+q], c1 = vsm[80+q], c2 = vsm[96+q], c3 = vsm[112+q];
        s0 += xv.x*a0.x + xv.y*a0.y + xv.z*a0.z + xv.w*a0.w;
        s1 += xv.x*a1.x + xv.y*a1.y + xv.z*a1.z + xv.w*a1.w;
        s2 += xv.x*a2.x + xv.y*a2.y + xv.z*a2.z + xv.w*a2.w;
        s3 += xv.x*a3.x + xv.y*a3.y + xv.z*a3.z + xv.w*a3.w;
        d0 += xv.x*c0.x + xv.y*c0.y + xv.z*c0.z + xv.w*c0.w;
        d1 += xv.x*c1.x + xv.y*c1.y + xv.z*c1.z + xv.w*c1.w;
        d2 += xv.x*c2.x + xv.y*c2.y + xv.z*c2.z + xv.w*c2.w;
        d3 += xv.x*c3.x + xv.y*c3.y + xv.z*c3.z + xv.w*c3.w;
    }
    *(float4*)&a_s[(size_t)i * 4] = make_float4(s0, s1, s2, s3);
    *(float4*)&a_d[(size_t)i * 4] = make_float4(d0, d1, d2, d3);
}

// ---------------- K3 (MFMA): xw(bf16-packed) = x @ W_gat^T + boundary detect ----------
// 16x16x32 bf16 MFMA. A = x (64 rows), split hi/lo bf16 planes (removes x-quant error);
// B = W_gat rows-as-columns (B[k][c] = Wg[c][k], stored [c][k]). XOR-swizzled LDS (G4).
// Wave w owns col-tiles {ct0, ct0+1, ct0+4, ct0+5}, pairing c with c+64 for the pack.
__launch_bounds__(256)
__global__ void k_gemm1m(const float* __restrict__ x, const float* __restrict__ Wg,
                         const int* __restrict__ batch_idx,
                         uint32_t* __restrict__ xwp, int* __restrict__ startg, int N)
{
    __shared__ __align__(16) uint32_t AsH[2048];   // 64 rows x 32 k-pairs (bf16x2)
    __shared__ __align__(16) uint32_t AsL[2048];
    __shared__ __align__(16) uint32_t BsH[8192];   // 256 cols x 32 k-pairs
    const int tid = threadIdx.x;
    const int r0  = blockIdx.x * 64;

    // stage A (x rows, hi/lo split): uint idx = (r*32 + k2) ^ ((r&7)<<2)
    for (int idx = tid; idx < 2048; idx += 256) {
        int r = idx >> 5, k2 = idx & 31;
        float2 v = make_float2(0.f, 0.f);
        if (r0 + r < N) v = *(const float2*)&x[(size_t)(r0 + r) * 64 + 2 * k2];
        unsigned short h0 = f2bf(v.x), h1 = f2bf(v.y);
        unsigned short l0 = f2bf(v.x - bf2f(h0)), l1 = f2bf(v.y - bf2f(h1));
        int di = (r * 32 + k2) ^ ((r & 7) << 2);
        AsH[di] = (uint32_t)h0 | ((uint32_t)h1 << 16);
        AsL[di] = (uint32_t)l0 | ((uint32_t)l1 << 16);
    }
    // stage B (Wg as-is: row c = output channel, 64 k)
    for (int idx = tid; idx < 8192; idx += 256) {
        int c = idx >> 5, k2 = idx & 31;
        float2 v = *(const float2*)&Wg[(size_t)c * 64 + 2 * k2];
        int di = (c * 32 + k2) ^ ((c & 7) << 2);
        BsH[di] = (uint32_t)f2bf(v.x) | ((uint32_t)f2bf(v.y) << 16);
    }
    if (tid < 64 && (r0 + tid) < N) {
        int i = r0 + tid;
        int b = batch_idx[i];
        int pb = (i > 0) ? batch_idx[i - 1] : -1;
        if (b != pb) startg[b] = i;
    }
    __syncthreads();

    const int lane = tid & 63;
    const int wv   = tid >> 6;
    const int rl   = lane & 15;             // row (A) / col (B) within tile
    const int kg   = lane >> 4;             // k-group
    const int ct0  = (wv & 1) * 2 + (wv >> 1) * 8;
    const int swz  = (rl & 7) << 2;

    f32x4 acc[4][4];
    #pragma unroll
    for (int r = 0; r < 4; ++r)
        #pragma unroll
        for (int cs = 0; cs < 4; ++cs) acc[r][cs] = (f32x4){0.f, 0.f, 0.f, 0.f};

    #pragma unroll
    for (int ks = 0; ks < 2; ++ks) {
        bf16x8 aH[4], aL[4], bH[4];
        #pragma unroll
        for (int r = 0; r < 4; ++r) {
            int ui = (((r * 16 + rl) * 32) + ks * 16 + kg * 4) ^ swz;
            aH[r] = *(const bf16x8*)&AsH[ui];
            aL[r] = *(const bf16x8*)&AsL[ui];
        }
        #pragma unroll
        for (int cs = 0; cs < 4; ++cs) {
            int ct = ct0 + (cs & 1) + (cs >> 1) * 4;
            int ui = (((ct * 16 + rl) * 32) + ks * 16 + kg * 4) ^ swz;
            bH[cs] = *(const bf16x8*)&BsH[ui];
        }
        #pragma unroll
        for (int r = 0; r < 4; ++r)
            #pragma unroll
            for (int cs = 0; cs < 4; ++cs) {
                acc[r][cs] = __builtin_amdgcn_mfma_f32_16x16x32_bf16(aH[r], bH[cs], acc[r][cs], 0, 0, 0);
                acc[r][cs] = __builtin_amdgcn_mfma_f32_16x16x32_bf16(aL[r], bH[cs], acc[r][cs], 0, 0, 0);
            }
    }

    // epilogue: C layout col=lane&15, row=(lane>>4)*4+reg (m89). Pack (c, c+64).
    #pragma unroll
    for (int r = 0; r < 4; ++r) {
        #pragma unroll
        for (int reg = 0; reg < 4; ++reg) {
            int row = r0 + r * 16 + kg * 4 + reg;
            if (row < N) {
                #pragma unroll
                for (int p = 0; p < 2; ++p) {
                    int c_lo = (ct0 + p) * 16 + rl;
                    int wrd  = ((c_lo >> 7) << 6) | (c_lo & 63);
                    uint32_t lo = f2bf(acc[r][p][reg]);
                    uint32_t hi = f2bf(acc[r][p + 2][reg]);
                    xwp[(size_t)row * 128 + wrd] = lo | (hi << 16);
                }
            }
        }
    }
}

// ---------------- K5/K6/K7: exclusive scan of deg -> off, cursor; graph inv_sqrt --------
__global__ void k_scan1(const int* __restrict__ deg, int* __restrict__ off,
                        int* __restrict__ bsum, int N)
{
    __shared__ int s[256];
    int t = threadIdx.x;
    int i = blockIdx.x * 256 + t;
    int v = (i < N) ? deg[i] : 0;
    s[t] = v; __syncthreads();
    for (int o = 1; o < 256; o <<= 1) {
        int u = (t >= o) ? s[t - o] : 0;
        __syncthreads();
        s[t] += u;
        __syncthreads();
    }
    int incl = s[t];
    if (i < N) off[i] = incl - v;
    if (t == 255) bsum[blockIdx.x] = incl;
}

__global__ void k_scan2(const int* __restrict__ bsum, int* __restrict__ bpre,
                        int* __restrict__ off, const int* __restrict__ startg,
                        float* __restrict__ invs, int NB, int N)
{
    __shared__ int s[256];
    int t = threadIdx.x;
    int v = (t < NB) ? bsum[t] : 0;
    s[t] = v; __syncthreads();
    for (int o = 1; o < 256; o <<= 1) {
        int u = (t >= o) ? s[t - o] : 0;
        __syncthreads();
        s[t] += u;
        __syncthreads();
    }
    if (t < NB) bpre[t] = s[t] - v;
    if (t == 255) off[N] = s[255];
    if (t < 64) {
        int st = startg[t];
        int en = N;
        for (int g2 = t + 1; g2 < 64; ++g2) en = min(en, startg[g2]);
        int d = en - st;
        float dv = (d > 0) ? (float)d : 1.0f;
        invs[t] = 1.0f / sqrtf(dv);
    }
}

__global__ void k_scan3(int* __restrict__ off, int* __restrict__ cursor,
                        const int* __restrict__ bpre, int N)
{
    int i = blockIdx.x * blockDim.x + threadIdx.x;
    if (i >= N) return;
    int v = off[i] + bpre[blockIdx.x];
    off[i] = v;
    cursor[i] = v;
}

// ---------------- K8: CSR fill (dst-sorted source list) ----------------
__global__ void k_fill(const int* __restrict__ ei, int* __restrict__ cursor,
                       int* __restrict__ csr, int E)
{
    int e = blockIdx.x * blockDim.x + threadIdx.x;
    if (e >= E) return;
    int r = ei[e];
    int c = ei[E + e];
    int pos = atomicAdd(cursor + c, 1);
    csr[pos] = r;
}

// ---------------- K9 (v4): bf16-packed gathers, 4-edge unroll, head-pair phases -------
__launch_bounds__(256)
__global__ void k_main4(const uint32_t* __restrict__ xwp,
                        const float* __restrict__ a_s,
                        const float* __restrict__ a_d,
                        const int* __restrict__ off,
                        const int* __restrict__ csr,
                        const unsigned long long* __restrict__ magg,
                        const float* __restrict__ bias,
                        float* __restrict__ tb, int N)
{
    const int bid   = blockIdx.x;
    const int xcd   = bid & 7;
    const int phase = (xcd >= 4) ? 1 : 0;            // head pair {2p, 2p+1}
    const int pblk  = (bid >> 3) * 4 + (xcd & 3);
    const int lane  = threadIdx.x & 63;
    const int wv    = threadIdx.x >> 6;
    const int wid   = pblk * 4 + wv;
    const int nw    = 8192;                          // waves per phase

    const int fbase = phase * 128;
    const float b0c = bias[fbase + lane];
    const float b1c = bias[fbase + 64 + lane];
    const uint32_t* base = xwp + (size_t)phase * 64 + lane;   // row stride 128 uints

    for (int i = wid; i < N; i += nw) {
        const int beg = off[i], end = off[i + 1];
        const float2 ad2 = *(const float2*)(a_d + (size_t)i * 4 + phase * 2);
        const float2 as2 = *(const float2*)(a_s + (size_t)i * 4 + phase * 2);
        const float exa = __expf(lrelu(as2.x + ad2.x));
        const float exb = __expf(lrelu(as2.y + ad2.y));

        uint32_t sv = base[(size_t)i * 128];
        float accA0 = exa * bflo(sv), accA1 = exb * bfhi(sv);
        float accB0 = 0.f, accB1 = 0.f, accC0 = 0.f, accC1 = 0.f, accD0 = 0.f, accD1 = 0.f;
        float s0 = 0.f, s1 = 0.f;

        for (int kc = beg; kc < end; kc += 64) {
            const int cnt = min(64, end - kc);
            int sreg = 0; float e0 = 0.f, e1 = 0.f;
            if (lane < cnt) {
                sreg = csr[kc + lane];
                const float2 g = *(const float2*)(a_s + (size_t)sreg * 4 + phase * 2);
                e0 = __expf(lrelu(g.x + ad2.x));
                e1 = __expf(lrelu(g.y + ad2.y));
            }
            s0 += e0; s1 += e1;

            int j = 0;
            for (; j + 4 <= cnt; j += 4) {
                int sA = __shfl(sreg, j    ), sB = __shfl(sreg, j + 1);
                int sC = __shfl(sreg, j + 2), sD = __shfl(sreg, j + 3);
                float wA0 = __shfl(e0, j    ), wA1 = __shfl(e1, j    );
                float wB0 = __shfl(e0, j + 1), wB1 = __shfl(e1, j + 1);
                float wC0 = __shfl(e0, j + 2), wC1 = __shfl(e1, j + 2);
                float wD0 = __shfl(e0, j + 3), wD1 = __shfl(e1, j + 3);
                uint32_t vA = base[(size_t)sA * 128];
                uint32_t vB = base[(size_t)sB * 128];
                uint32_t vC = base[(size_t)sC * 128];
                uint32_t vD = base[(size_t)sD * 128];
                accA0 += wA0 * bflo(vA); accA1 += wA1 * bfhi(vA);
                accB0 += wB0 * bflo(vB); accB1 += wB1 * bfhi(vB);
                accC0 += wC0 * bflo(vC); accC1 += wC1 * bfhi(vC);
                accD0 += wD0 * bflo(vD); accD1 += wD1 * bfhi(vD);
            }
            for (; j < cnt; ++j) {
                int   s  = __shfl(sreg, j);
                float w0 = __shfl(e0, j);
                float w1 = __shfl(e1, j);
                uint32_t v = base[(size_t)s * 128];
                accA0 += w0 * bflo(v);
                accA1 += w1 * bfhi(v);
            }
        }
        float acc0 = (accA0 + accB0) + (accC0 + accD0);
        float acc1 = (accA1 + accB1) + (accC1 + accD1);
        #pragma unroll
        for (int o = 1; o < 64; o <<= 1) { s0 += __shfl_xor(s0, o); s1 += __shfl_xor(s1, o); }
        s0 += exa; s1 += exb;   // self-loop terms, counted once
        const float r0 = 1.0f / (s0 + 1e-16f);
        const float r1 = 1.0f / (s1 + 1e-16f);

        const unsigned long long mb = magg[i];
        const float mbit = (float)((mb >> lane) & 1ULL);   // mask feature = col & 63 = lane
        const size_t ob = (size_t)i * 256 + fbase + lane;
        tb[ob     ] = (acc0 * r0 + b0c) * mbit;
        tb[ob + 64] = (acc1 * r1 + b1c) * mbit;
    }
}

// ---------------- K10: out = tb @ W_lin^T + b_lin, * inv_sqrt[batch] (reg-weight) -------
__launch_bounds__(256, 4)
__global__ void k_gemm2r(const float* __restrict__ tb, const float* __restrict__ Wl,
                         const float* __restrict__ bl,
                         const int* __restrict__ batch_idx, const float* __restrict__ invs,
                         float* __restrict__ out, int N)
{
    __shared__ float ts[32 * 256];
    const int tid  = threadIdx.x;
    const int wv   = tid >> 6;
    const int lane = tid & 63;
    const int cl   = lane & 15;
    const int q    = lane >> 4;
    const int c    = wv * 16 + cl;
    const int r0   = blockIdx.x * 32;

    float4 w4[16];
    #pragma unroll
    for (int m = 0; m < 8; ++m) {
        w4[m*2+0] = *(const float4*)&Wl[(size_t)c * 256 + m*32 + q*8 + 0];
        w4[m*2+1] = *(const float4*)&Wl[(size_t)c * 256 + m*32 + q*8 + 4];
    }
    const float blc = bl[c];

    const float4* tb4 = (const float4*)tb;
    float4* ts4 = (float4*)ts;
    #pragma unroll
    for (int it = 0; it < 8; ++it) {
        int idx = tid + it * 256;
        int row = idx >> 6;
        float4 v = make_float4(0.f, 0.f, 0.f, 0.f);
        if (r0 + row < N) v = tb4[(size_t)r0 * 64 + idx];
        ts4[idx] = v;
    }
    __syncthreads();

    #pragma unroll
    for (int rb = 0; rb < 32; rb += 4) {
        float p[4];
        #pragma unroll
        for (int rr = 0; rr < 4; ++rr) {
            const float4* tr = ts4 + (rb + rr) * 64 + q * 2;
            float a = 0.f;
            #pragma unroll
            for (int m = 0; m < 8; ++m) {
                float4 t0 = tr[m*8 + 0];
                float4 t1 = tr[m*8 + 1];
                float4 u0 = w4[m*2+0], u1 = w4[m*2+1];
                a += t0.x*u0.x + t0.y*u0.y + t0.z*u0.z + t0.w*u0.w
                   + t1.x*u1.x + t1.y*u1.y + t1.z*u1.z + t1.w*u1.w;
            }
            a += __shfl_xor(a, 16);
            a += __shfl_xor(a, 32);
            p[rr] = a;
        }
        int rr  = lane >> 4;
        float val = (rr == 0) ? p[0] : (rr == 1) ? p[1] : (rr == 2) ? p[2] : p[3];
        int row = r0 + rb + rr;
        if (row < N) {
            float sc = invs[batch_idx[row]];
            out[(size_t)row * 64 + c] = (val + blc) * sc;
        }
    }
}

// ---------------- launcher ----------------
extern "C" void kernel_launch(void* const* d_in, const int* in_sizes, int n_in,
                              void* d_out, int out_size, void* d_ws, size_t ws_size,
                              hipStream_t stream)
{
    const float* x      = (const float*)d_in[0];
    const float* mask   = (const float*)d_in[1];
    const int*   ei     = (const int*)d_in[2];
    const int*   batch  = (const int*)d_in[3];
    const float* Wg     = (const float*)d_in[4];
    const float* att_s  = (const float*)d_in[5];
    const float* att_d  = (const float*)d_in[6];
    const float* bias_g = (const float*)d_in[7];
    const float* Wl     = (const float*)d_in[8];
    const float* bl     = (const float*)d_in[9];
    float* out = (float*)d_out;

    const int N = in_sizes[0] / 64;   // 50000
    const int E = in_sizes[2] / 2;    // 800000

    char* w = (char*)d_ws;
    auto alloc = [&](size_t bytes) { char* p = w; w += (bytes + 255) & ~(size_t)255; return p; };
    uint32_t* xwp  = (uint32_t*)alloc((size_t)N * 128 * 4);   // packed bf16 head-pairs
    float* tbuf  = (float*)alloc((size_t)N * 256 * 4);
    float* a_s   = (float*)alloc((size_t)N * 4 * 4);
    float* a_d   = (float*)alloc((size_t)N * 4 * 4);
    unsigned long long* mbits = (unsigned long long*)alloc((size_t)N * 8);
    unsigned long long* magg  = (unsigned long long*)alloc((size_t)N * 8);
    int* deg    = (int*)alloc((size_t)N * 4);
    int* off    = (int*)alloc((size_t)(N + 1) * 4);
    int* cursor = (int*)alloc((size_t)N * 4);
    int* csr    = (int*)alloc((size_t)E * 4);
    int* bsum   = (int*)alloc(256 * 4);
    int* bpre   = (int*)alloc(256 * 4);
    int* startg = (int*)alloc(64 * 4);
    float* invs = (float*)alloc(64 * 4);
    float* vs   = (float*)alloc(256 * 4);
    float* vd   = (float*)alloc(256 * 4);

    int nbN4  = (N + 3) / 4;       // one wave per node, 4 waves/block
    int nb256 = (N + 255) / 256;

    k_init<<<nbN4, 256, 0, stream>>>(mask, mbits, magg, deg, startg, N);
    k_edge_prep<<<(E + 255) / 256, 256, 0, stream>>>(ei, mbits, magg, deg, E);
    k_vprep<<<1, 256, 0, stream>>>(Wg, att_s, att_d, vs, vd);
    k_att<<<nb256, 256, 0, stream>>>(x, vs, vd, a_s, a_d, N);
    k_gemm1m<<<(N + 63) / 64, 256, 0, stream>>>(x, Wg, batch, xwp, startg, N);
    k_scan1<<<nb256, 256, 0, stream>>>(deg, off, bsum, N);
    k_scan2<<<1, 256, 0, stream>>>(bsum, bpre, off, startg, invs, nb256, N);
    k_scan3<<<nb256, 256, 0, stream>>>(off, cursor, bpre, N);
    k_fill<<<(E + 255) / 256, 256, 0, stream>>>(ei, cursor, csr, E);
    k_main4<<<4096, 256, 0, stream>>>(xwp, a_s, a_d, off, csr, magg, bias_g, tbuf, N);
    k_gemm2r<<<(N + 31) / 32, 256, 0, stream>>>(tbuf, Wl, bl, batch, invs, out, N);
}

// Round 8
// 259.307 us; speedup vs baseline: 1.5911x; 1.0714x over previous
//
#include <hip/hip_runtime.h>
#include <cstdint>
#include <math.h>

constexpr float NEG_SLOPE = 0.2f;

__device__ __forceinline__ float lrelu(float v) { return v > 0.0f ? v : NEG_SLOPE * v; }

// bf16 pack/unpack (RNE)
__device__ __forceinline__ unsigned short f2bf(float f) {
    uint32_t u = __float_as_uint(f);
    uint32_t r = (u + 0x7fffu + ((u >> 16) & 1u)) >> 16;
    return (unsigned short)r;
}
__device__ __forceinline__ float bf2f(unsigned short v) { return __uint_as_float((uint32_t)v << 16); }
__device__ __forceinline__ float bflo(uint32_t v) { return __uint_as_float(v << 16); }
__device__ __forceinline__ float bfhi(uint32_t v) { return __uint_as_float(v & 0xffff0000u); }

typedef short bf16x8 __attribute__((ext_vector_type(8)));   // 8 bf16 (4 VGPRs)
typedef float f32x4 __attribute__((ext_vector_type(4)));

// ---------------- K1: per-node init + mask bits (one wave per node) ----------------
__global__ void k_init(const float* __restrict__ mask,
                       unsigned long long* __restrict__ mbits,
                       unsigned long long* __restrict__ magg,
                       int* __restrict__ deg, int* __restrict__ startg, int N)
{
    if (blockIdx.x == 0 && threadIdx.x < 64) startg[threadIdx.x] = N;
    int wid  = (blockIdx.x * blockDim.x + threadIdx.x) >> 6;
    int lane = threadIdx.x & 63;
    if (wid >= N) return;
    float v = mask[(size_t)wid * 64 + lane];
    unsigned long long b = __ballot(v > 0.0f);
    if (lane == 0) { mbits[wid] = b; magg[wid] = 0ULL; deg[wid] = 0; }
}

// ---------------- K2: edge pass: mask OR scatter (col->row) + in-degree histogram ----
__global__ void k_edge_prep(const int* __restrict__ ei,
                            const unsigned long long* __restrict__ mbits,
                            unsigned long long* __restrict__ magg,
                            int* __restrict__ deg, int E)
{
    int e = blockIdx.x * blockDim.x + threadIdx.x;
    if (e >= E) return;
    int r = ei[e];
    int c = ei[E + e];
    unsigned long long b = mbits[c];
    if ((magg[r] & b) != b) atomicOr(magg + r, b);
    atomicAdd(deg + c, 1);
}

// ---------------- K_att2: a_s/a_d per node; v_s/v_d recomputed per block (vprep fused) --
__launch_bounds__(256)
__global__ void k_att2(const float* __restrict__ x, const float* __restrict__ Wg,
                       const float* __restrict__ att_s, const float* __restrict__ att_d,
                       float* __restrict__ a_s, float* __restrict__ a_d, int N)
{
    __shared__ float vs_l[256];
    __shared__ float vd_l[256];
    int tid = threadIdx.x;
    {   // vprep: vs[h][k] = sum_d Wg[h*64+d][k] * att_s[h][d]   (Wg 64KB, L2-hot)
        int h = tid >> 6, k = tid & 63;
        float s = 0.f, d = 0.f;
        for (int dd = 0; dd < 64; ++dd) {
            float w = Wg[(size_t)(h * 64 + dd) * 64 + k];
            s += w * att_s[h * 64 + dd];
            d += w * att_d[h * 64 + dd];
        }
        vs_l[tid] = s; vd_l[tid] = d;
    }
    __syncthreads();
    int i = blockIdx.x * 256 + tid;
    if (i >= N) return;
    const float4* xr = (const float4*)(x + (size_t)i * 64);
    float s0=0,s1=0,s2=0,s3=0, d0=0,d1=0,d2=0,d3=0;
    #pragma unroll
    for (int q = 0; q < 16; ++q) {
        float4 xv = xr[q];
        float4 a0 = *(const float4*)&vs_l[4*q];
        float4 a1 = *(const float4*)&vs_l[64 + 4*q];
        float4 a2 = *(const float4*)&vs_l[128 + 4*q];
        float4 a3 = *(const float4*)&vs_l[192 + 4*q];
        float4 c0 = *(const float4*)&vd_l[4*q];
        float4 c1 = *(const float4*)&vd_l[64 + 4*q];
        float4 c2 = *(const float4*)&vd_l[128 + 4*q];
        float4 c3 = *(const float4*)&vd_l[192 + 4*q];
        s0 += xv.x*a0.x + xv.y*a0.y + xv.z*a0.z + xv.w*a0.w;
        s1 += xv.x*a1.x + xv.y*a1.y + xv.z*a1.z + xv.w*a1.w;
        s2 += xv.x*a2.x + xv.y*a2.y + xv.z*a2.z + xv.w*a2.w;
        s3 += xv.x*a3.x + xv.y*a3.y + xv.z*a3.z + xv.w*a3.w;
        d0 += xv.x*c0.x + xv.y*c0.y + xv.z*c0.z + xv.w*c0.w;
        d1 += xv.x*c1.x + xv.y*c1.y + xv.z*c1.z + xv.w*c1.w;
        d2 += xv.x*c2.x + xv.y*c2.y + xv.z*c2.z + xv.w*c2.w;
        d3 += xv.x*c3.x + xv.y*c3.y + xv.z*c3.z + xv.w*c3.w;
    }
    *(float4*)&a_s[(size_t)i * 4] = make_float4(s0, s1, s2, s3);
    *(float4*)&a_d[(size_t)i * 4] = make_float4(d0, d1, d2, d3);
}

// ---------------- K3 (MFMA): xw(bf16-packed) = x @ W_gat^T + boundary detect ----------
__launch_bounds__(256)
__global__ void k_gemm1m(const float* __restrict__ x, const float* __restrict__ Wg,
                         const int* __restrict__ batch_idx,
                         uint32_t* __restrict__ xwp, int* __restrict__ startg, int N)
{
    __shared__ __align__(16) uint32_t AsH[2048];   // 64 rows x 32 k-pairs (bf16x2)
    __shared__ __align__(16) uint32_t AsL[2048];
    __shared__ __align__(16) uint32_t BsH[8192];   // 256 cols x 32 k-pairs
    const int tid = threadIdx.x;
    const int r0  = blockIdx.x * 64;

    for (int idx = tid; idx < 2048; idx += 256) {
        int r = idx >> 5, k2 = idx & 31;
        float2 v = make_float2(0.f, 0.f);
        if (r0 + r < N) v = *(const float2*)&x[(size_t)(r0 + r) * 64 + 2 * k2];
        unsigned short h0 = f2bf(v.x), h1 = f2bf(v.y);
        unsigned short l0 = f2bf(v.x - bf2f(h0)), l1 = f2bf(v.y - bf2f(h1));
        int di = (r * 32 + k2) ^ ((r & 7) << 2);
        AsH[di] = (uint32_t)h0 | ((uint32_t)h1 << 16);
        AsL[di] = (uint32_t)l0 | ((uint32_t)l1 << 16);
    }
    for (int idx = tid; idx < 8192; idx += 256) {
        int c = idx >> 5, k2 = idx & 31;
        float2 v = *(const float2*)&Wg[(size_t)c * 64 + 2 * k2];
        int di = (c * 32 + k2) ^ ((c & 7) << 2);
        BsH[di] = (uint32_t)f2bf(v.x) | ((uint32_t)f2bf(v.y) << 16);
    }
    if (tid < 64 && (r0 + tid) < N) {
        int i = r0 + tid;
        int b = batch_idx[i];
        int pb = (i > 0) ? batch_idx[i - 1] : -1;
        if (b != pb) startg[b] = i;
    }
    __syncthreads();

    const int lane = tid & 63;
    const int wv   = tid >> 6;
    const int rl   = lane & 15;
    const int kg   = lane >> 4;
    const int ct0  = (wv & 1) * 2 + (wv >> 1) * 8;
    const int swz  = (rl & 7) << 2;

    f32x4 acc[4][4];
    #pragma unroll
    for (int r = 0; r < 4; ++r)
        #pragma unroll
        for (int cs = 0; cs < 4; ++cs) acc[r][cs] = (f32x4){0.f, 0.f, 0.f, 0.f};

    #pragma unroll
    for (int ks = 0; ks < 2; ++ks) {
        bf16x8 aH[4], aL[4], bH[4];
        #pragma unroll
        for (int r = 0; r < 4; ++r) {
            int ui = (((r * 16 + rl) * 32) + ks * 16 + kg * 4) ^ swz;
            aH[r] = *(const bf16x8*)&AsH[ui];
            aL[r] = *(const bf16x8*)&AsL[ui];
        }
        #pragma unroll
        for (int cs = 0; cs < 4; ++cs) {
            int ct = ct0 + (cs & 1) + (cs >> 1) * 4;
            int ui = (((ct * 16 + rl) * 32) + ks * 16 + kg * 4) ^ swz;
            bH[cs] = *(const bf16x8*)&BsH[ui];
        }
        #pragma unroll
        for (int r = 0; r < 4; ++r)
            #pragma unroll
            for (int cs = 0; cs < 4; ++cs) {
                acc[r][cs] = __builtin_amdgcn_mfma_f32_16x16x32_bf16(aH[r], bH[cs], acc[r][cs], 0, 0, 0);
                acc[r][cs] = __builtin_amdgcn_mfma_f32_16x16x32_bf16(aL[r], bH[cs], acc[r][cs], 0, 0, 0);
            }
    }

    #pragma unroll
    for (int r = 0; r < 4; ++r) {
        #pragma unroll
        for (int reg = 0; reg < 4; ++reg) {
            int row = r0 + r * 16 + kg * 4 + reg;
            if (row < N) {
                #pragma unroll
                for (int p = 0; p < 2; ++p) {
                    int c_lo = (ct0 + p) * 16 + rl;
                    int wrd  = ((c_lo >> 7) << 6) | (c_lo & 63);
                    uint32_t lo = f2bf(acc[r][p][reg]);
                    uint32_t hi = f2bf(acc[r][p + 2][reg]);
                    xwp[(size_t)row * 128 + wrd] = lo | (hi << 16);
                }
            }
        }
    }
}

// ---------------- K5/K6/K7: exclusive scan of deg -> off, cursor; graph inv_sqrt --------
__global__ void k_scan1(const int* __restrict__ deg, int* __restrict__ off,
                        int* __restrict__ bsum, int N)
{
    __shared__ int s[256];
    int t = threadIdx.x;
    int i = blockIdx.x * 256 + t;
    int v = (i < N) ? deg[i] : 0;
    s[t] = v; __syncthreads();
    for (int o = 1; o < 256; o <<= 1) {
        int u = (t >= o) ? s[t - o] : 0;
        __syncthreads();
        s[t] += u;
        __syncthreads();
    }
    int incl = s[t];
    if (i < N) off[i] = incl - v;
    if (t == 255) bsum[blockIdx.x] = incl;
}

__global__ void k_scan2(const int* __restrict__ bsum, int* __restrict__ bpre,
                        int* __restrict__ off, const int* __restrict__ startg,
                        float* __restrict__ invs, int NB, int N)
{
    __shared__ int s[256];
    int t = threadIdx.x;
    int v = (t < NB) ? bsum[t] : 0;
    s[t] = v; __syncthreads();
    for (int o = 1; o < 256; o <<= 1) {
        int u = (t >= o) ? s[t - o] : 0;
        __syncthreads();
        s[t] += u;
        __syncthreads();
    }
    if (t < NB) bpre[t] = s[t] - v;
    if (t == 255) off[N] = s[255];
    if (t < 64) {
        int st = startg[t];
        int en = N;
        for (int g2 = t + 1; g2 < 64; ++g2) en = min(en, startg[g2]);
        int d = en - st;
        float dv = (d > 0) ? (float)d : 1.0f;
        invs[t] = 1.0f / sqrtf(dv);
    }
}

__global__ void k_scan3(int* __restrict__ off, int* __restrict__ cursor,
                        const int* __restrict__ bpre, int N)
{
    int i = blockIdx.x * blockDim.x + threadIdx.x;
    if (i >= N) return;
    int v = off[i] + bpre[blockIdx.x];
    off[i] = v;
    cursor[i] = v;
}

// ---------------- K8: CSR fill (dst-sorted source list) ----------------
__global__ void k_fill(const int* __restrict__ ei, int* __restrict__ cursor,
                       int* __restrict__ csr, int E)
{
    int e = blockIdx.x * blockDim.x + threadIdx.x;
    if (e >= E) return;
    int r = ei[e];
    int c = ei[E + e];
    int pos = atomicAdd(cursor + c, 1);
    csr[pos] = r;
}

// ---------------- K9 (v5): single pass, all 4 heads per wave, LDS chunk-stage ----------
// Lane l owns uint2 {word 2l, 2l+1} of the 128-word xwp row = head-pair hp=l>>5,
// features d0=2*(l&31), d0+1. Per 64-edge chunk: (sreg, e0..e3) staged in LDS once,
// inner loop = broadcast ds_reads (no per-edge shuffles), 4 gathers in flight.
__launch_bounds__(256)
__global__ void k_main5(const uint32_t* __restrict__ xwp,
                        const float* __restrict__ a_s,
                        const float* __restrict__ a_d,
                        const int* __restrict__ off,
                        const int* __restrict__ csr,
                        const unsigned long long* __restrict__ magg,
                        const float* __restrict__ bias,
                        float* __restrict__ tb, int N)
{
    __shared__ __align__(16) uint32_t su[4][64];
    __shared__ float2 e01s[4][64];
    __shared__ float2 e23s[4][64];

    const int lane = threadIdx.x & 63;
    const int wv   = threadIdx.x >> 6;
    const int wid  = blockIdx.x * 4 + wv;
    const int nw   = gridDim.x * 4;
    const int hp   = lane >> 5;           // head pair
    const int d0   = (lane & 31) * 2;     // feature base (0..62 even)

    const uint2* xw2 = (const uint2*)xwp;            // row stride 64 uint2
    const float2 bsL = *(const float2*)&bias[hp * 128 + d0];
    const float2 bsH = *(const float2*)&bias[hp * 128 + 64 + d0];
    const float2* ep = hp ? e23s[wv] : e01s[wv];

    for (int i = wid; i < N; i += nw) {
        const int beg = off[i], end = off[i + 1];
        const float4 adv = *(const float4*)(a_d + (size_t)i * 4);
        const float4 asv = *(const float4*)(a_s + (size_t)i * 4);
        const float ex0 = __expf(lrelu(asv.x + adv.x));
        const float ex1 = __expf(lrelu(asv.y + adv.y));
        const float ex2 = __expf(lrelu(asv.z + adv.z));
        const float ex3 = __expf(lrelu(asv.w + adv.w));

        const uint2 sv = xw2[(size_t)i * 64 + lane];
        const float wls = hp ? ex2 : ex0;
        const float whs = hp ? ex3 : ex1;
        float accL0 = wls * bflo(sv.x), accH0 = whs * bfhi(sv.x);
        float accL1 = wls * bflo(sv.y), accH1 = whs * bfhi(sv.y);
        float s0 = 0.f, s1 = 0.f, s2 = 0.f, s3 = 0.f;

        for (int kc = beg; kc < end; kc += 64) {
            const int cnt = min(64, end - kc);
            uint32_t sreg = 0; float e0 = 0.f, e1 = 0.f, e2 = 0.f, e3 = 0.f;
            if (lane < cnt) {
                sreg = csr[kc + lane];
                const float4 g = *(const float4*)(a_s + (size_t)sreg * 4);
                e0 = __expf(lrelu(g.x + adv.x));
                e1 = __expf(lrelu(g.y + adv.y));
                e2 = __expf(lrelu(g.z + adv.z));
                e3 = __expf(lrelu(g.w + adv.w));
            }
            s0 += e0; s1 += e1; s2 += e2; s3 += e3;
            su[wv][lane]   = sreg;
            e01s[wv][lane] = make_float2(e0, e1);
            e23s[wv][lane] = make_float2(e2, e3);

            int j = 0;
            for (; j + 4 <= cnt; j += 4) {
                uint4 sq = *(const uint4*)&su[wv][j];
                float2 wA = ep[j], wB = ep[j+1], wC = ep[j+2], wD = ep[j+3];
                uint2 vA = xw2[(size_t)sq.x * 64 + lane];
                uint2 vB = xw2[(size_t)sq.y * 64 + lane];
                uint2 vC = xw2[(size_t)sq.z * 64 + lane];
                uint2 vD = xw2[(size_t)sq.w * 64 + lane];
                accL0 += wA.x * bflo(vA.x); accH0 += wA.y * bfhi(vA.x);
                accL1 += wA.x * bflo(vA.y); accH1 += wA.y * bfhi(vA.y);
                accL0 += wB.x * bflo(vB.x); accH0 += wB.y * bfhi(vB.x);
                accL1 += wB.x * bflo(vB.y); accH1 += wB.y * bfhi(vB.y);
                accL0 += wC.x * bflo(vC.x); accH0 += wC.y * bfhi(vC.x);
                accL1 += wC.x * bflo(vC.y); accH1 += wC.y * bfhi(vC.y);
                accL0 += wD.x * bflo(vD.x); accH0 += wD.y * bfhi(vD.x);
                accL1 += wD.x * bflo(vD.y); accH1 += wD.y * bfhi(vD.y);
            }
            for (; j < cnt; ++j) {
                uint32_t s = su[wv][j];
                float2 wE = ep[j];
                uint2 v = xw2[(size_t)s * 64 + lane];
                accL0 += wE.x * bflo(v.x); accH0 += wE.y * bfhi(v.x);
                accL1 += wE.x * bflo(v.y); accH1 += wE.y * bfhi(v.y);
            }
        }
        #pragma unroll
        for (int o = 1; o < 64; o <<= 1) {
            s0 += __shfl_xor(s0, o); s1 += __shfl_xor(s1, o);
            s2 += __shfl_xor(s2, o); s3 += __shfl_xor(s3, o);
        }
        s0 += ex0; s1 += ex1; s2 += ex2; s3 += ex3;   // self-loop, counted once
        const float slo = hp ? s2 : s0;
        const float shi = hp ? s3 : s1;
        const float rlo = 1.0f / (slo + 1e-16f);
        const float rhi = 1.0f / (shi + 1e-16f);

        const unsigned long long mb = magg[i];
        const float m0 = (float)((mb >> d0) & 1ULL);
        const float m1 = (float)((mb >> (d0 + 1)) & 1ULL);
        float2 oL = make_float2((accL0 * rlo + bsL.x) * m0, (accL1 * rlo + bsL.y) * m1);
        float2 oH = make_float2((accH0 * rhi + bsH.x) * m0, (accH1 * rhi + bsH.y) * m1);
        *(float2*)&tb[(size_t)i * 256 + hp * 128 + d0]      = oL;
        *(float2*)&tb[(size_t)i * 256 + hp * 128 + 64 + d0] = oH;
    }
}

// ---------------- K10 (MFMA): out = tb @ W_lin^T + b_lin, * inv_sqrt[batch] ------------
// 64 rows/block, K=256 staged in 4 chunks of 64. Hi/lo split on BOTH operands
// (3 MFMAs: aH*bH + aH*bL + aL*bH) -> quantization error ~2^-16, negligible.
__launch_bounds__(256)
__global__ void k_gemm2m(const float* __restrict__ tb, const float* __restrict__ Wl,
                         const float* __restrict__ bl,
                         const int* __restrict__ batch_idx, const float* __restrict__ invs,
                         float* __restrict__ out, int N)
{
    __shared__ __align__(16) uint32_t AH[2048];   // 64 rows x 32 k-pairs
    __shared__ __align__(16) uint32_t AL[2048];
    __shared__ __align__(16) uint32_t BH[2048];   // 64 cols x 32 k-pairs
    __shared__ __align__(16) uint32_t BL[2048];
    const int tid = threadIdx.x;
    const int r0  = blockIdx.x * 64;
    const int lane = tid & 63;
    const int wv   = tid >> 6;
    const int rl   = lane & 15;
    const int kg   = lane >> 4;
    const int swz  = (rl & 7) << 2;

    f32x4 acc[4];
    #pragma unroll
    for (int r = 0; r < 4; ++r) acc[r] = (f32x4){0.f, 0.f, 0.f, 0.f};

    for (int kc = 0; kc < 4; ++kc) {
        if (kc) __syncthreads();
        for (int idx = tid; idx < 2048; idx += 256) {
            int r = idx >> 5, k2 = idx & 31;
            float2 v = make_float2(0.f, 0.f);
            if (r0 + r < N) v = *(const float2*)&tb[(size_t)(r0 + r) * 256 + kc * 64 + 2 * k2];
            unsigned short h0 = f2bf(v.x), h1 = f2bf(v.y);
            unsigned short l0 = f2bf(v.x - bf2f(h0)), l1 = f2bf(v.y - bf2f(h1));
            int di = (r * 32 + k2) ^ ((r & 7) << 2);
            AH[di] = (uint32_t)h0 | ((uint32_t)h1 << 16);
            AL[di] = (uint32_t)l0 | ((uint32_t)l1 << 16);
        }
        for (int idx = tid; idx < 2048; idx += 256) {
            int c = idx >> 5, k2 = idx & 31;
            float2 v = *(const float2*)&Wl[(size_t)c * 256 + kc * 64 + 2 * k2];
            unsigned short h0 = f2bf(v.x), h1 = f2bf(v.y);
            unsigned short l0 = f2bf(v.x - bf2f(h0)), l1 = f2bf(v.y - bf2f(h1));
            int di = (c * 32 + k2) ^ ((c & 7) << 2);
            BH[di] = (uint32_t)h0 | ((uint32_t)h1 << 16);
            BL[di] = (uint32_t)l0 | ((uint32_t)l1 << 16);
        }
        __syncthreads();

        #pragma unroll
        for (int ks = 0; ks < 2; ++ks) {
            int uib = ((wv * 16 + rl) * 32 + ks * 16 + kg * 4) ^ swz;
            bf16x8 bHf = *(const bf16x8*)&BH[uib];
            bf16x8 bLf = *(const bf16x8*)&BL[uib];
            #pragma unroll
            for (int r = 0; r < 4; ++r) {
                int ui = ((r * 16 + rl) * 32 + ks * 16 + kg * 4) ^ swz;
                bf16x8 aHf = *(const bf16x8*)&AH[ui];
                bf16x8 aLf = *(const bf16x8*)&AL[ui];
                acc[r] = __builtin_amdgcn_mfma_f32_16x16x32_bf16(aHf, bHf, acc[r], 0, 0, 0);
                acc[r] = __builtin_amdgcn_mfma_f32_16x16x32_bf16(aHf, bLf, acc[r], 0, 0, 0);
                acc[r] = __builtin_amdgcn_mfma_f32_16x16x32_bf16(aLf, bHf, acc[r], 0, 0, 0);
            }
        }
    }

    // C layout: col = lane&15 (within wave's 16-col tile), row = r*16 + kg*4 + reg
    const int col = wv * 16 + rl;
    const float blc = bl[col];
    #pragma unroll
    for (int r = 0; r < 4; ++r) {
        #pragma unroll
        for (int reg = 0; reg < 4; ++reg) {
            int row = r0 + r * 16 + kg * 4 + reg;
            if (row < N) {
                float sc = invs[batch_idx[row]];
                out[(size_t)row * 64 + col] = (acc[r][reg] + blc) * sc;
            }
        }
    }
}

// ---------------- launcher ----------------
extern "C" void kernel_launch(void* const* d_in, const int* in_sizes, int n_in,
                              void* d_out, int out_size, void* d_ws, size_t ws_size,
                              hipStream_t stream)
{
    const float* x      = (const float*)d_in[0];
    const float* mask   = (const float*)d_in[1];
    const int*   ei     = (const int*)d_in[2];
    const int*   batch  = (const int*)d_in[3];
    const float* Wg     = (const float*)d_in[4];
    const float* att_s  = (const float*)d_in[5];
    const float* att_d  = (const float*)d_in[6];
    const float* bias_g = (const float*)d_in[7];
    const float* Wl     = (const float*)d_in[8];
    const float* bl     = (const float*)d_in[9];
    float* out = (float*)d_out;

    const int N = in_sizes[0] / 64;   // 50000
    const int E = in_sizes[2] / 2;    // 800000

    char* w = (char*)d_ws;
    auto alloc = [&](size_t bytes) { char* p = w; w += (bytes + 255) & ~(size_t)255; return p; };
    uint32_t* xwp  = (uint32_t*)alloc((size_t)N * 128 * 4);   // packed bf16 head-pairs
    float* tbuf  = (float*)alloc((size_t)N * 256 * 4);
    float* a_s   = (float*)alloc((size_t)N * 4 * 4);
    float* a_d   = (float*)alloc((size_t)N * 4 * 4);
    unsigned long long* mbits = (unsigned long long*)alloc((size_t)N * 8);
    unsigned long long* magg  = (unsigned long long*)alloc((size_t)N * 8);
    int* deg    = (int*)alloc((size_t)N * 4);
    int* off    = (int*)alloc((size_t)(N + 1) * 4);
    int* cursor = (int*)alloc((size_t)N * 4);
    int* csr    = (int*)alloc((size_t)E * 4);
    int* bsum   = (int*)alloc(256 * 4);
    int* bpre   = (int*)alloc(256 * 4);
    int* startg = (int*)alloc(64 * 4);
    float* invs = (float*)alloc(64 * 4);

    int nbN4  = (N + 3) / 4;       // one wave per node, 4 waves/block
    int nb256 = (N + 255) / 256;

    k_init<<<nbN4, 256, 0, stream>>>(mask, mbits, magg, deg, startg, N);
    k_edge_prep<<<(E + 255) / 256, 256, 0, stream>>>(ei, mbits, magg, deg, E);
    k_att2<<<nb256, 256, 0, stream>>>(x, Wg, att_s, att_d, a_s, a_d, N);
    k_gemm1m<<<(N + 63) / 64, 256, 0, stream>>>(x, Wg, batch, xwp, startg, N);
    k_scan1<<<nb256, 256, 0, stream>>>(deg, off, bsum, N);
    k_scan2<<<1, 256, 0, stream>>>(bsum, bpre, off, startg, invs, nb256, N);
    k_scan3<<<nb256, 256, 0, stream>>>(off, cursor, bpre, N);
    k_fill<<<(E + 255) / 256, 256, 0, stream>>>(ei, cursor, csr, E);
    k_main5<<<2048, 256, 0, stream>>>(xwp, a_s, a_d, off, csr, magg, bias_g, tbuf, N);
    k_gemm2m<<<(N + 63) / 64, 256, 0, stream>>>(tbuf, Wl, bl, batch, invs, out, N);
}